// Round 1
// baseline (551.430 us; speedup 1.0000x reference)
//
#include <hip/hip_runtime.h>

#define DIM 768
#define NHEADS 12
#define HDIM 64
#define BATCH 2
#define SEQ 2048
#define ROWS (BATCH*SEQ)   // 4096
#define KSPLIT 2

typedef __attribute__((ext_vector_type(8))) _Float16 f16x8;
typedef __attribute__((ext_vector_type(4))) _Float16 f16x4;
typedef __attribute__((ext_vector_type(4))) float    f32x4;

// ---------------- fp32 -> fp16 conversion (vectorized x4) ----------------
__global__ void cvt4(const float4* __restrict__ s, f16x4* __restrict__ d, int n4) {
    int i = blockIdx.x * 256 + threadIdx.x;
    if (i < n4) {
        float4 v = s[i];
        f16x4 o;
        o[0] = (_Float16)v.x; o[1] = (_Float16)v.y;
        o[2] = (_Float16)v.z; o[3] = (_Float16)v.w;
        d[i] = o;
    }
}

// ---------------- C[M][N] = A[M][K] * B[N][K]^T, fp16 in/out -------------
// block = 256 thr = 4 waves; 64x64 tile; each wave 32x32 (2x2 of 16x16).
// A-frag: A[m=lane&15][k=quad*8+j]  (16B contiguous row loads)
// B-frag: B element B[n=lane&15][k=quad*8+j] (16B contiguous row loads)
// C-tile: row=(lane>>4)*4+reg, col=lane&15   [measured layout, m89/m91]
__global__ __launch_bounds__(256) void gemm_bt_f16(
    const _Float16* __restrict__ A, const _Float16* __restrict__ Bm,
    _Float16* __restrict__ C, int M, int N, int K)
{
    const int lane = threadIdx.x & 63;
    const int w    = threadIdx.x >> 6;
    const int c    = lane & 15, quad = lane >> 4;
    const int ntiles = N >> 6;
    const int mt = (blockIdx.x / ntiles) << 6;
    const int nt = (blockIdx.x % ntiles) << 6;
    const int wm = mt + ((w >> 1) << 5);
    const int wn = nt + ((w & 1) << 5);

    f32x4 acc[2][2] = {};
    for (int k0 = 0; k0 < K; k0 += 32) {
        const int col = k0 + quad * 8;
        f16x8 a[2], b[2];
#pragma unroll
        for (int i = 0; i < 2; ++i)
            a[i] = *reinterpret_cast<const f16x8*>(A + (size_t)(wm + i*16 + c) * K + col);
#pragma unroll
        for (int j = 0; j < 2; ++j)
            b[j] = *reinterpret_cast<const f16x8*>(Bm + (size_t)(wn + j*16 + c) * K + col);
#pragma unroll
        for (int i = 0; i < 2; ++i)
#pragma unroll
            for (int j = 0; j < 2; ++j)
                acc[i][j] = __builtin_amdgcn_mfma_f32_16x16x32_f16(a[i], b[j], acc[i][j], 0, 0, 0);
    }
#pragma unroll
    for (int i = 0; i < 2; ++i)
#pragma unroll
        for (int j = 0; j < 2; ++j)
#pragma unroll
            for (int r = 0; r < 4; ++r) {
                int m = wm + i*16 + quad*4 + r;
                int n = wn + j*16 + c;
                C[(size_t)m * N + n] = (_Float16)acc[i][j][r];
            }
}

// ---------------- fused attention with heads-softmax ---------------------
// grid: 2 batches x 128 q-tiles(16) x KSPLIT  = 512 blocks, 4 waves/block.
// Per 128-key iteration: wave w scores its 32 keys for ALL 12 heads
// (softmax over heads is in-register: same lane/reg slot across the 12 accs),
// writes P to LDS; then wave w computes PV for ITS 3 heads over all 128 keys.
// P_lds row padded to 40 halves (80B stride: 16B-aligned, conflict-light).
__global__ __launch_bounds__(256) void attn_kernel(
    const _Float16* __restrict__ Q,   // [4096][768]
    const _Float16* __restrict__ Km,  // [4096][768]
    const _Float16* __restrict__ Vt,  // [768][4096]
    float* __restrict__ out)          // [4096][768] fp32 (zeroed; atomicAdd)
{
    __shared__ _Float16 P_lds[4 * 12 * 16 * 40];   // 60 KB
    const int lane = threadIdx.x & 63;
    const int w    = threadIdx.x >> 6;
    const int c    = lane & 15, quad = lane >> 4;

    const int bid = blockIdx.x;
    const int ks  = bid & (KSPLIT - 1);
    const int qt  = (bid >> 1) & 127;
    const int b   = bid >> 8;
    const int qrow0 = b * SEQ + qt * 16;
    const int kbase = ks * (SEQ / KSPLIT);

    f32x4 o_acc[3][4] = {};   // [3 owned heads][4 d-tiles of 16]

    for (int it = 0; it < (SEQ / KSPLIT) / 128; ++it) {
        const int k0 = kbase + it * 128;   // block's 128 keys this iter
        const int kw = k0 + w * 32;        // this wave's 32 keys
        // ---- phase 1: scores + heads-softmax + P write (16 keys/sub) ----
#pragma unroll
        for (int sub = 0; sub < 2; ++sub) {
            const int krow0 = b * SEQ + kw + sub * 16;
            f32x4 s[12];
#pragma unroll
            for (int h = 0; h < 12; ++h) {
                f32x4 acc = {};
#pragma unroll
                for (int dc = 0; dc < 2; ++dc) {
                    const int col = h * 64 + dc * 32 + quad * 8;
                    f16x8 aq = *reinterpret_cast<const f16x8*>(Q  + (size_t)(qrow0 + c) * DIM + col);
                    f16x8 bk = *reinterpret_cast<const f16x8*>(Km + (size_t)(krow0 + c) * DIM + col);
                    acc = __builtin_amdgcn_mfma_f32_16x16x32_f16(aq, bk, acc, 0, 0, 0);
                }
                s[h] = acc;   // S[q=quad*4+r][key=kw+sub*16+c]
            }
#pragma unroll
            for (int r = 0; r < 4; ++r) {
                float m = s[0][r];
#pragma unroll
                for (int h = 1; h < 12; ++h) m = fmaxf(m, s[h][r]);
                float p[12]; float sum = 0.f;
#pragma unroll
                for (int h = 0; h < 12; ++h) { p[h] = __expf(s[h][r] - m); sum += p[h]; }
                const float inv = 1.0f / (sum * 27.712812921102035f);  // /sqrt(768)
#pragma unroll
                for (int h = 0; h < 12; ++h)
                    P_lds[((w*12 + h)*16 + quad*4 + r)*40 + sub*16 + c] = (_Float16)(p[h] * inv);
            }
        }
        __syncthreads();
        // ---- phase 2: PV for this wave's 3 heads over all 128 keys ----
#pragma unroll
        for (int hh = 0; hh < 3; ++hh) {
            const int h = w * 3 + hh;
#pragma unroll
            for (int kc = 0; kc < 4; ++kc) {   // kc = writing wave's chunk
                f16x8 ap = *reinterpret_cast<const f16x8*>(
                    &P_lds[((kc*12 + h)*16 + c)*40 + quad*8]);   // A[q=c][k=quad*8+j]
#pragma unroll
                for (int dt = 0; dt < 4; ++dt) {
                    const _Float16* vp = Vt + (size_t)(h*64 + dt*16 + c) * ROWS
                                            + (b * SEQ + k0 + kc*32 + quad*8);
                    f16x8 bv = *reinterpret_cast<const f16x8*>(vp);
                    o_acc[hh][dt] = __builtin_amdgcn_mfma_f32_16x16x32_f16(ap, bv, o_acc[hh][dt], 0, 0, 0);
                }
            }
        }
        __syncthreads();
    }
    // ---- epilogue: atomic accumulate fp32 (KSPLIT partial sums) ----
#pragma unroll
    for (int hh = 0; hh < 3; ++hh) {
        const int h = w * 3 + hh;
#pragma unroll
        for (int dt = 0; dt < 4; ++dt)
#pragma unroll
            for (int r = 0; r < 4; ++r) {
                const int row = qrow0 + quad*4 + r;
                const int col = h*64 + dt*16 + c;
                atomicAdd(&out[(size_t)row * DIM + col], o_acc[hh][dt][r]);
            }
    }
}

// ------------------------------- launch ----------------------------------
extern "C" void kernel_launch(void* const* d_in, const int* in_sizes, int n_in,
                              void* d_out, int out_size, void* d_ws, size_t ws_size,
                              hipStream_t stream)
{
    const float* x  = (const float*)d_in[0];
    const float* Wq = (const float*)d_in[1];
    const float* Wk = (const float*)d_in[2];
    const float* Wv = (const float*)d_in[3];

    _Float16* ws  = (_Float16*)d_ws;
    _Float16* xb  = ws;                       // 4096x768
    _Float16* wqb = xb  + (size_t)ROWS * DIM; // 768x768
    _Float16* wkb = wqb + (size_t)DIM * DIM;
    _Float16* wvb = wkb + (size_t)DIM * DIM;
    _Float16* Qh  = wvb + (size_t)DIM * DIM;  // 4096x768
    _Float16* Kh  = Qh  + (size_t)ROWS * DIM; // 4096x768
    _Float16* Vth = Kh  + (size_t)ROWS * DIM; // 768x4096 (V transposed)

    // fp32 -> fp16
    cvt4<<<(ROWS*DIM/4 + 255)/256, 256, 0, stream>>>((const float4*)x,  (f16x4*)xb,  ROWS*DIM/4);
    cvt4<<<(DIM*DIM/4  + 255)/256, 256, 0, stream>>>((const float4*)Wq, (f16x4*)wqb, DIM*DIM/4);
    cvt4<<<(DIM*DIM/4  + 255)/256, 256, 0, stream>>>((const float4*)Wk, (f16x4*)wkb, DIM*DIM/4);
    cvt4<<<(DIM*DIM/4  + 255)/256, 256, 0, stream>>>((const float4*)Wv, (f16x4*)wvb, DIM*DIM/4);

    // projections: Q = x Wq^T, K = x Wk^T  (row-major [4096][768])
    gemm_bt_f16<<<(ROWS/64)*(DIM/64), 256, 0, stream>>>(xb, wqb, Qh, ROWS, DIM, DIM);
    gemm_bt_f16<<<(ROWS/64)*(DIM/64), 256, 0, stream>>>(xb, wkb, Kh, ROWS, DIM, DIM);
    // Vt = Wv x^T : C[o][row] = sum_k Wv[o][k] x[row][k] -> [768][4096]
    gemm_bt_f16<<<(DIM/64)*(ROWS/64), 256, 0, stream>>>(wvb, xb, Vth, DIM, ROWS, DIM);

    // fused attention, accumulating into zeroed fp32 out
    hipMemsetAsync(d_out, 0, (size_t)out_size * sizeof(float), stream);
    attn_kernel<<<BATCH * (SEQ/16) * KSPLIT, 256, 0, stream>>>(Qh, Kh, Vth, (float*)d_out);
}

// Round 2
// 332.386 us; speedup vs baseline: 1.6590x; 1.6590x over previous
//
#include <hip/hip_runtime.h>

#define DIM 768
#define NHEADS 12
#define HDIM 64
#define BATCH 2
#define SEQ 2048
#define ROWS (BATCH*SEQ)   // 4096
#define KSPLIT 2
#define KT24 (DIM/32)      // 24 frag col-tiles across 768

typedef __attribute__((ext_vector_type(8))) _Float16 f16x8;
typedef __attribute__((ext_vector_type(4))) float    f32x4;

// ============================================================
// Fragment layout F(mt, kt): frag tile = 16 rows x 32 cols of a
// row-major matrix M[R][C]:  frag[lane][j] = M[mt*16 + (lane&15)]
//                                             [kt*32 + (lane>>4)*8 + j]
// stored at  dst[ ((mt*(C/32) + kt)*64 + lane)*8 ]  (halves).
// A-frag and B-frag of mfma_f32_16x16x32_f16 use the SAME mapping,
// so this layout serves x, Wq, Wk, Wv, Q, K, and Vt uniformly.
// ============================================================

// ---- fp32 row-major -> f16 fragment layout (one wave per tile) ----
__global__ __launch_bounds__(256) void cvt_frag(
    const float* __restrict__ src, _Float16* __restrict__ dst, int R, int C)
{
    const int lane = threadIdx.x & 63;
    const int wid  = (blockIdx.x * 256 + threadIdx.x) >> 6;
    const int tc   = C >> 5;
    const int mt   = wid / tc, kt = wid % tc;
    if (mt * 16 >= R) return;
    const int c = lane & 15, quad = lane >> 4;
    const float* p = src + (size_t)(mt*16 + c) * C + kt*32 + quad*8;
    float4 v0 = *(const float4*)p;
    float4 v1 = *(const float4*)(p + 4);
    f16x8 o;
    o[0]=(_Float16)v0.x; o[1]=(_Float16)v0.y; o[2]=(_Float16)v0.z; o[3]=(_Float16)v0.w;
    o[4]=(_Float16)v1.x; o[5]=(_Float16)v1.y; o[6]=(_Float16)v1.z; o[7]=(_Float16)v1.w;
    *reinterpret_cast<f16x8*>(dst + ((size_t)wid * 64 + lane) * 8) = o;
}

// ---- C = A * B^T with frag-layout inputs AND frag-layout output ----
// block = 4 waves, 64x64 tile, wave = 32x32 (2x2 of 16x16 MFMA).
// Epilogue: per-wave 32x32 LDS transpose (C-layout -> frag layout),
// then coalesced f16x8 global stores.
__global__ __launch_bounds__(256) void gemm_f(
    const _Float16* __restrict__ Af, const _Float16* __restrict__ Bf,
    _Float16* __restrict__ Cf, int M, int N, int K)
{
    __shared__ _Float16 lds[4][32 * 40];
    const int lane = threadIdx.x & 63;
    const int w    = threadIdx.x >> 6;
    const int c    = lane & 15, quad = lane >> 4;
    const int ntiles = N >> 6;
    const int mt = (blockIdx.x / ntiles) << 6;
    const int nt = (blockIdx.x % ntiles) << 6;
    const int wm = mt + ((w >> 1) << 5);
    const int wn = nt + ((w & 1) << 5);
    const int KT = K >> 5;

    f32x4 acc[2][2] = {};
    for (int kt = 0; kt < KT; ++kt) {
        f16x8 a[2], b[2];
#pragma unroll
        for (int i = 0; i < 2; ++i)
            a[i] = *reinterpret_cast<const f16x8*>(
                Af + (((size_t)(wm/16 + i) * KT + kt) * 64 + lane) * 8);
#pragma unroll
        for (int j = 0; j < 2; ++j)
            b[j] = *reinterpret_cast<const f16x8*>(
                Bf + (((size_t)(wn/16 + j) * KT + kt) * 64 + lane) * 8);
#pragma unroll
        for (int i = 0; i < 2; ++i)
#pragma unroll
            for (int j = 0; j < 2; ++j)
                acc[i][j] = __builtin_amdgcn_mfma_f32_16x16x32_f16(a[i], b[j], acc[i][j], 0, 0, 0);
    }
    // C-layout (row=quad*4+r, col=c) -> LDS
    _Float16* L = lds[w];
#pragma unroll
    for (int i = 0; i < 2; ++i)
#pragma unroll
        for (int j = 0; j < 2; ++j)
#pragma unroll
            for (int r = 0; r < 4; ++r)
                L[(i*16 + quad*4 + r) * 40 + j*16 + c] = (_Float16)acc[i][j][r];
    __syncthreads();
    // frag layout out: row=c, col=quad*8+j  (32-wide kt tile = wn/32)
    const int NT = N >> 5;
#pragma unroll
    for (int i2 = 0; i2 < 2; ++i2) {
        f16x8 v = *reinterpret_cast<const f16x8*>(&L[(i2*16 + c) * 40 + quad*8]);
        *reinterpret_cast<f16x8*>(
            Cf + (((size_t)((wm + i2*16) >> 4) * NT + (wn >> 5)) * 64 + lane) * 8) = v;
    }
}

// ---- fused attention, heads-softmax, frag-layout operands ----
// grid: 2 batches x 128 q-tiles x KSPLIT = 512 blocks, 4 waves.
// Q frags hoisted to registers (96 VGPRs); all global loads coalesced.
// ks==0 blocks store to d_out, ks==1 to partial buffer (no atomics).
__global__ __launch_bounds__(256, 2) void attn_kernel(
    const _Float16* __restrict__ Qf,   // frags of Q[4096][768]
    const _Float16* __restrict__ Kf,   // frags of K[4096][768]
    const _Float16* __restrict__ Vtf,  // frags of Vt[768][4096]
    float* __restrict__ out,           // [4096][768]
    float* __restrict__ part)          // [4096][768]
{
    __shared__ _Float16 P_lds[4 * 12 * 16 * 40];   // 60 KB
    const int lane = threadIdx.x & 63;
    const int w    = threadIdx.x >> 6;
    const int c    = lane & 15, quad = lane >> 4;

    const int bid = blockIdx.x;
    const int ks  = bid & (KSPLIT - 1);
    const int qt  = (bid >> 1) & 127;
    const int b   = bid >> 8;
    const int qrow0 = b * SEQ + qt * 16;
    const int qt16  = qrow0 >> 4;
    const int kbase = ks * (SEQ / KSPLIT);

    // hoist all 24 Q fragments for this q-tile
    f16x8 qreg[24];
#pragma unroll
    for (int i = 0; i < 24; ++i)
        qreg[i] = *reinterpret_cast<const f16x8*>(
            Qf + (((size_t)qt16 * KT24 + i) * 64 + lane) * 8);

    f32x4 o_acc[3][4] = {};   // [3 owned heads][4 d-tiles]

    for (int it = 0; it < (SEQ / KSPLIT) / 128; ++it) {
        const int k0 = kbase + it * 128;
        const int kw = k0 + w * 32;
        // ---- phase 1: scores + heads-softmax ----
#pragma unroll
        for (int sub = 0; sub < 2; ++sub) {
            const int ktile = (b * SEQ + kw + sub * 16) >> 4;
            f32x4 s[12];
#pragma unroll
            for (int h = 0; h < 12; ++h) {
                f32x4 acc = {};
#pragma unroll
                for (int dc = 0; dc < 2; ++dc) {
                    f16x8 bk = *reinterpret_cast<const f16x8*>(
                        Kf + (((size_t)ktile * KT24 + h*2 + dc) * 64 + lane) * 8);
                    acc = __builtin_amdgcn_mfma_f32_16x16x32_f16(qreg[h*2+dc], bk, acc, 0, 0, 0);
                }
                s[h] = acc;   // S[q=quad*4+r][key=kw+sub*16+c]
            }
#pragma unroll
            for (int r = 0; r < 4; ++r) {
                float m = s[0][r];
#pragma unroll
                for (int h = 1; h < 12; ++h) m = fmaxf(m, s[h][r]);
                float p[12]; float sum = 0.f;
#pragma unroll
                for (int h = 0; h < 12; ++h) { p[h] = __expf(s[h][r] - m); sum += p[h]; }
                const float inv = 1.0f / (sum * 27.712812921102035f);  // /sqrt(768)
#pragma unroll
                for (int h = 0; h < 12; ++h)
                    P_lds[((w*12 + h)*16 + quad*4 + r)*40 + sub*16 + c] = (_Float16)(p[h] * inv);
            }
        }
        __syncthreads();
        // ---- phase 2: PV for this wave's 3 heads ----
#pragma unroll
        for (int hh = 0; hh < 3; ++hh) {
            const int h = w * 3 + hh;
#pragma unroll
            for (int kc = 0; kc < 4; ++kc) {
                f16x8 ap = *reinterpret_cast<const f16x8*>(
                    &P_lds[((kc*12 + h)*16 + c)*40 + quad*8]);
#pragma unroll
                for (int dt = 0; dt < 4; ++dt) {
                    f16x8 bv = *reinterpret_cast<const f16x8*>(
                        Vtf + (((size_t)(h*4 + dt) * (ROWS>>5)
                               + ((b*SEQ + k0 + kc*32) >> 5)) * 64 + lane) * 8);
                    o_acc[hh][dt] = __builtin_amdgcn_mfma_f32_16x16x32_f16(ap, bv, o_acc[hh][dt], 0, 0, 0);
                }
            }
        }
        __syncthreads();
    }
    // ---- epilogue: plain coalesced-ish stores (no atomics) ----
    float* dst = ks ? part : out;
#pragma unroll
    for (int hh = 0; hh < 3; ++hh) {
        const int h = w * 3 + hh;
#pragma unroll
        for (int dt = 0; dt < 4; ++dt)
#pragma unroll
            for (int r = 0; r < 4; ++r) {
                const int row = qrow0 + quad*4 + r;
                const int col = h*64 + dt*16 + c;
                dst[(size_t)row * DIM + col] = o_acc[hh][dt][r];
            }
    }
}

// ---- out += part, vectorized ----
__global__ __launch_bounds__(256) void reduce_add(
    float4* __restrict__ out, const float4* __restrict__ part, int n4)
{
    int i = blockIdx.x * 256 + threadIdx.x;
    if (i < n4) {
        float4 a = out[i], b = part[i];
        a.x += b.x; a.y += b.y; a.z += b.z; a.w += b.w;
        out[i] = a;
    }
}

// ------------------------------- launch ----------------------------------
extern "C" void kernel_launch(void* const* d_in, const int* in_sizes, int n_in,
                              void* d_out, int out_size, void* d_ws, size_t ws_size,
                              hipStream_t stream)
{
    const float* x  = (const float*)d_in[0];
    const float* Wq = (const float*)d_in[1];
    const float* Wk = (const float*)d_in[2];
    const float* Wv = (const float*)d_in[3];

    _Float16* ws  = (_Float16*)d_ws;
    const size_t XS = (size_t)ROWS * DIM;   // 3145728 halves
    const size_t WS = (size_t)DIM * DIM;    // 589824 halves
    _Float16* xf  = ws;
    _Float16* wqf = xf  + XS;
    _Float16* wkf = wqf + WS;
    _Float16* wvf = wkf + WS;
    _Float16* Qf  = wvf + WS;
    _Float16* Kf  = Qf  + XS;
    _Float16* Vtf = Kf  + XS;
    float*    part = (float*)(Vtf + XS);    // 4096x768 fp32 (12 MB)

    // fp32 -> f16 fragment layout
    cvt_frag<<<(ROWS/16)*(DIM/32)/4, 256, 0, stream>>>(x,  xf,  ROWS, DIM);
    cvt_frag<<<(DIM/16)*(DIM/32)/4,  256, 0, stream>>>(Wq, wqf, DIM, DIM);
    cvt_frag<<<(DIM/16)*(DIM/32)/4,  256, 0, stream>>>(Wk, wkf, DIM, DIM);
    cvt_frag<<<(DIM/16)*(DIM/32)/4,  256, 0, stream>>>(Wv, wvf, DIM, DIM);

    // Q = x Wq^T, K = x Wk^T  (frag-layout out over [4096][768])
    gemm_f<<<(ROWS/64)*(DIM/64), 256, 0, stream>>>(xf, wqf, Qf, ROWS, DIM, DIM);
    gemm_f<<<(ROWS/64)*(DIM/64), 256, 0, stream>>>(xf, wkf, Kf, ROWS, DIM, DIM);
    // Vt = Wv x^T  (frag-layout out over [768][4096])
    gemm_f<<<(DIM/64)*(ROWS/64), 256, 0, stream>>>(wvf, xf, Vtf, DIM, ROWS, DIM);

    // fused attention (ks=0 -> d_out, ks=1 -> part), then reduce
    attn_kernel<<<BATCH * (SEQ/16) * KSPLIT, 256, 0, stream>>>(
        Qf, Kf, Vtf, (float*)d_out, part);
    reduce_add<<<(ROWS*DIM/4 + 255)/256, 256, 0, stream>>>(
        (float4*)d_out, (const float4*)part, ROWS*DIM/4);
}

// Round 3
// 325.200 us; speedup vs baseline: 1.6957x; 1.0221x over previous
//
#include <hip/hip_runtime.h>

#define DIM 768
#define NHEADS 12
#define HDIM 64
#define BATCH 2
#define SEQ 2048
#define ROWS (BATCH*SEQ)   // 4096
#define KSPLIT 4
#define KT24 (DIM/32)      // 24 frag col-tiles across 768

typedef __attribute__((ext_vector_type(8))) _Float16 f16x8;
typedef __attribute__((ext_vector_type(4))) _Float16 f16x4;
typedef __attribute__((ext_vector_type(4))) float    f32x4;

// ============================================================
// Fragment layout F(mt, kt): 16 rows x 32 cols of row-major M[R][C]:
//   frag[lane][j] = M[mt*16 + (lane&15)][kt*32 + (lane>>4)*8 + j]
// stored at dst[((mt*(C/32) + kt)*64 + lane)*8] (halves).
// Identical mapping for A- and B-operands of mfma_f32_16x16x32_f16.
// ============================================================

__global__ __launch_bounds__(256) void cvt_frag(
    const float* __restrict__ src, _Float16* __restrict__ dst, int R, int C)
{
    const int lane = threadIdx.x & 63;
    const int wid  = (blockIdx.x * 256 + threadIdx.x) >> 6;
    const int tc   = C >> 5;
    const int mt   = wid / tc, kt = wid % tc;
    if (mt * 16 >= R) return;
    const int c = lane & 15, quad = lane >> 4;
    const float* p = src + (size_t)(mt*16 + c) * C + kt*32 + quad*8;
    float4 v0 = *(const float4*)p;
    float4 v1 = *(const float4*)(p + 4);
    f16x8 o;
    o[0]=(_Float16)v0.x; o[1]=(_Float16)v0.y; o[2]=(_Float16)v0.z; o[3]=(_Float16)v0.w;
    o[4]=(_Float16)v1.x; o[5]=(_Float16)v1.y; o[6]=(_Float16)v1.z; o[7]=(_Float16)v1.w;
    *reinterpret_cast<f16x8*>(dst + ((size_t)wid * 64 + lane) * 8) = o;
}

// ---- C = A * B^T, frag-layout in/out. K must be 768 (24 kt, 4 groups of 6).
// Batch-of-6 kt: 24 loads in flight per group -> 4 latency exposures/block.
__global__ __launch_bounds__(256) void gemm_f(
    const _Float16* __restrict__ Af, const _Float16* __restrict__ Bf,
    _Float16* __restrict__ Cf, int M, int N, int K)
{
    __shared__ _Float16 lds[4][32 * 40];
    const int lane = threadIdx.x & 63;
    const int w    = threadIdx.x >> 6;
    const int c    = lane & 15, quad = lane >> 4;
    const int ntiles = N >> 6;
    const int mt = (blockIdx.x / ntiles) << 6;
    const int nt = (blockIdx.x % ntiles) << 6;
    const int wm = mt + ((w >> 1) << 5);
    const int wn = nt + ((w & 1) << 5);
    const int KT = K >> 5;

    f32x4 acc[2][2] = {};
    for (int g = 0; g < KT / 6; ++g) {
        f16x8 a[6][2], b[6][2];
#pragma unroll
        for (int u = 0; u < 6; ++u) {
            const int kt = g*6 + u;
#pragma unroll
            for (int i = 0; i < 2; ++i)
                a[u][i] = *reinterpret_cast<const f16x8*>(
                    Af + (((size_t)(wm/16 + i) * KT + kt) * 64 + lane) * 8);
#pragma unroll
            for (int j = 0; j < 2; ++j)
                b[u][j] = *reinterpret_cast<const f16x8*>(
                    Bf + (((size_t)(wn/16 + j) * KT + kt) * 64 + lane) * 8);
        }
#pragma unroll
        for (int u = 0; u < 6; ++u)
#pragma unroll
            for (int i = 0; i < 2; ++i)
#pragma unroll
                for (int j = 0; j < 2; ++j)
                    acc[i][j] = __builtin_amdgcn_mfma_f32_16x16x32_f16(a[u][i], b[u][j], acc[i][j], 0, 0, 0);
    }
    _Float16* L = lds[w];
#pragma unroll
    for (int i = 0; i < 2; ++i)
#pragma unroll
        for (int j = 0; j < 2; ++j)
#pragma unroll
            for (int r = 0; r < 4; ++r)
                L[(i*16 + quad*4 + r) * 40 + j*16 + c] = (_Float16)acc[i][j][r];
    __syncthreads();
    const int NT = N >> 5;
#pragma unroll
    for (int i2 = 0; i2 < 2; ++i2) {
        f16x8 v = *reinterpret_cast<const f16x8*>(&L[(i2*16 + c) * 40 + quad*8]);
        *reinterpret_cast<f16x8*>(
            Cf + (((size_t)((wm + i2*16) >> 4) * NT + (wn >> 5)) * 64 + lane) * 8) = v;
    }
}

// ---- fused attention, heads-softmax ----
// grid: bid = (b*KSPLIT + ks)*64 + qb  (qb in low bits: same-(b,ks) blocks
// cluster on each XCD for L2 locality). Block = 32 q rows, 512 keys,
// 16 iters x 32 keys. Phase 1: wave w -> qtile (w>>1), key-half (w&1);
// wave pairs (0,2)/(1,3) share K frags via L1. Phase 2: wave w -> qtile
// (w>>1), dt-half (w&1); pairs share V frags via L1. Q staged in LDS once.
__global__ __launch_bounds__(256, 2) void attn_kernel(
    const _Float16* __restrict__ Qf, const _Float16* __restrict__ Kf,
    const _Float16* __restrict__ Vtf,
    float* __restrict__ out,          // ks==0 partial (covers all elements)
    _Float16* __restrict__ part)      // [3][4096][768] f16 partials ks=1..3
{
    __shared__ _Float16 Qlds[48 * 512];            // 48 KB
    __shared__ _Float16 P_lds[2 * 12 * 16 * 40];   // 30 KB (stride 40: 16B-aligned b128)
    const int tid = threadIdx.x;
    const int lane = tid & 63, w = tid >> 6;
    const int c = lane & 15, quad = lane >> 4;

    const int bid = blockIdx.x;
    const int qb = bid & 63;
    const int ks = (bid >> 6) & (KSPLIT - 1);
    const int b  = bid >> 8;
    const int qrow0 = b * SEQ + qb * 32;
    const int qt16  = qrow0 >> 4;

    // stage 48 Q frags (2 qtiles x 24), linear copy
    {
        const f16x8* src = reinterpret_cast<const f16x8*>(Qf + (size_t)qt16 * 24 * 512);
        f16x8* dst = reinterpret_cast<f16x8*>(Qlds);
#pragma unroll
        for (int i = 0; i < 12; ++i)
            dst[i * 256 + tid] = src[i * 256 + tid];
    }
    __syncthreads();

    const int kbase = b * SEQ + ks * (SEQ / KSPLIT);
    const int qi = w >> 1;          // phase-1/2 q-tile
    const int kj = w & 1;           // phase-1 key-half
    const int dthalf = w & 1;       // phase-2 dt-half

    f32x4 o_acc[12][2] = {};        // 96 VGPRs

    for (int it = 0; it < (SEQ / KSPLIT) / 32; ++it) {
        const int k0 = kbase + it * 32;
        // ---------- phase 1: 16q x 16k x 12h scores ----------
        const int kt16 = (k0 + kj * 16) >> 4;
        f32x4 s[12];
#pragma unroll
        for (int g = 0; g < 2; ++g) {           // heads 6g..6g+5
            f16x8 kf[12];
#pragma unroll
            for (int i = 0; i < 12; ++i)        // frag j = g*12+i (contiguous)
                kf[i] = *reinterpret_cast<const f16x8*>(
                    Kf + ((size_t)kt16 * 24 + g*12 + i) * 512 + lane * 8);
#pragma unroll
            for (int hh = 0; hh < 6; ++hh) {
                f16x8 q0 = *reinterpret_cast<const f16x8*>(
                    Qlds + (qi*24 + g*12 + hh*2    ) * 512 + lane * 8);
                f16x8 q1 = *reinterpret_cast<const f16x8*>(
                    Qlds + (qi*24 + g*12 + hh*2 + 1) * 512 + lane * 8);
                f32x4 acc = {};
                acc = __builtin_amdgcn_mfma_f32_16x16x32_f16(q0, kf[hh*2],   acc, 0, 0, 0);
                acc = __builtin_amdgcn_mfma_f32_16x16x32_f16(q1, kf[hh*2+1], acc, 0, 0, 0);
                s[g*6 + hh] = acc;              // S[q=quad*4+r][k=kj*16+c]
            }
        }
        // softmax over heads (in-register), write P
#pragma unroll
        for (int r = 0; r < 4; ++r) {
            float m = s[0][r];
#pragma unroll
            for (int h = 1; h < 12; ++h) m = fmaxf(m, s[h][r]);
            float p[12]; float sum = 0.f;
#pragma unroll
            for (int h = 0; h < 12; ++h) { p[h] = __expf(s[h][r] - m); sum += p[h]; }
            const float inv = 1.0f / (sum * 27.712812921102035f);   // /sqrt(768)
#pragma unroll
            for (int h = 0; h < 12; ++h)
                P_lds[((qi*12 + h)*16 + quad*4 + r)*40 + kj*16 + c] = (_Float16)(p[h] * inv);
        }
        __syncthreads();
        // ---------- phase 2: PV, 16q x 32k, 12h x 2dt ----------
        const int kt32 = k0 >> 5;
#pragma unroll
        for (int g = 0; g < 2; ++g) {           // heads 6g..6g+5
            f16x8 vf[12];
#pragma unroll
            for (int i = 0; i < 12; ++i) {      // i = hh*2 + dd
                const int h  = g*6 + (i >> 1);
                const int dt = dthalf*2 + (i & 1);
                vf[i] = *reinterpret_cast<const f16x8*>(
                    Vtf + ((size_t)(h*4 + dt) * (ROWS >> 5) + kt32) * 512 + lane * 8);
            }
#pragma unroll
            for (int hh = 0; hh < 6; ++hh) {
                const int h = g*6 + hh;
                f16x8 pf = *reinterpret_cast<const f16x8*>(
                    &P_lds[((qi*12 + h)*16 + c)*40 + quad*8]);
                o_acc[h][0] = __builtin_amdgcn_mfma_f32_16x16x32_f16(pf, vf[hh*2],   o_acc[h][0], 0, 0, 0);
                o_acc[h][1] = __builtin_amdgcn_mfma_f32_16x16x32_f16(pf, vf[hh*2+1], o_acc[h][1], 0, 0, 0);
            }
        }
        __syncthreads();
    }
    // ---------- epilogue ----------
#pragma unroll
    for (int h = 0; h < 12; ++h)
#pragma unroll
        for (int dd = 0; dd < 2; ++dd) {
            const int col = h*64 + (dthalf*2 + dd)*16 + c;
#pragma unroll
            for (int r = 0; r < 4; ++r) {
                const int row = qrow0 + qi*16 + quad*4 + r;
                if (ks == 0)
                    out[(size_t)row * DIM + col] = o_acc[h][dd][r];
                else
                    part[((size_t)(ks-1) * ROWS + row) * DIM + col] = (_Float16)o_acc[h][dd][r];
            }
        }
}

// ---- out += sum of 3 f16 partials ----
__global__ __launch_bounds__(256) void reduce_add4(
    float* __restrict__ out, const _Float16* __restrict__ part, int n4)
{
    int i = blockIdx.x * 256 + threadIdx.x;
    if (i >= n4) return;
    float4 o = reinterpret_cast<float4*>(out)[i];
    const size_t N = (size_t)ROWS * DIM;
#pragma unroll
    for (int p = 0; p < 3; ++p) {
        f16x4 v = reinterpret_cast<const f16x4*>(part + p * N)[i];
        o.x += (float)v[0]; o.y += (float)v[1]; o.z += (float)v[2]; o.w += (float)v[3];
    }
    reinterpret_cast<float4*>(out)[i] = o;
}

// ------------------------------- launch ----------------------------------
extern "C" void kernel_launch(void* const* d_in, const int* in_sizes, int n_in,
                              void* d_out, int out_size, void* d_ws, size_t ws_size,
                              hipStream_t stream)
{
    const float* x  = (const float*)d_in[0];
    const float* Wq = (const float*)d_in[1];
    const float* Wk = (const float*)d_in[2];
    const float* Wv = (const float*)d_in[3];

    _Float16* ws  = (_Float16*)d_ws;
    const size_t XS = (size_t)ROWS * DIM;   // 3145728
    const size_t WS = (size_t)DIM * DIM;    // 589824
    _Float16* xf   = ws;
    _Float16* wqf  = xf  + XS;
    _Float16* wkf  = wqf + WS;
    _Float16* wvf  = wkf + WS;
    _Float16* Qf   = wvf + WS;
    _Float16* Kf   = Qf  + XS;
    _Float16* Vtf  = Kf  + XS;
    _Float16* part = Vtf + XS;              // 3 * XS f16 partials

    cvt_frag<<<(ROWS/16)*(DIM/32)/4, 256, 0, stream>>>(x,  xf,  ROWS, DIM);
    cvt_frag<<<(DIM/16)*(DIM/32)/4,  256, 0, stream>>>(Wq, wqf, DIM, DIM);
    cvt_frag<<<(DIM/16)*(DIM/32)/4,  256, 0, stream>>>(Wk, wkf, DIM, DIM);
    cvt_frag<<<(DIM/16)*(DIM/32)/4,  256, 0, stream>>>(Wv, wvf, DIM, DIM);

    gemm_f<<<(ROWS/64)*(DIM/64), 256, 0, stream>>>(xf, wqf, Qf, ROWS, DIM, DIM);
    gemm_f<<<(ROWS/64)*(DIM/64), 256, 0, stream>>>(xf, wkf, Kf, ROWS, DIM, DIM);
    gemm_f<<<(DIM/64)*(ROWS/64), 256, 0, stream>>>(wvf, xf, Vtf, DIM, ROWS, DIM);

    attn_kernel<<<BATCH * KSPLIT * 64, 256, 0, stream>>>(
        Qf, Kf, Vtf, (float*)d_out, part);
    reduce_add4<<<(int)(XS/4 + 255)/256, 256, 0, stream>>>(
        (float*)d_out, part, (int)(XS/4));
}